// Round 5
// baseline (152.671 us; speedup 1.0000x reference)
//
#include <hip/hip_runtime.h>
#include <float.h>
#include <limits.h>

// Problem constants: B=64, Q=256 proposals, G=64 max GT, C=768 (unused).
#define QN 256
#define GN 64

typedef float fv64 __attribute__((ext_vector_type(64)));

__device__ __forceinline__ double mkdbl(int lo, int hi) { return __hiloint2double(hi, lo); }

// One 64-lane wave per batch; ALL state in registers. Lane t owns columns
// 4t..4t+3; cost lives in four 64-wide register vectors indexed ONLY by
// compile-time constants (uniform switch on row i; rule #20: runtime indexing
// would go to scratch). Exact JV semantics (f64, numpy op order) so the
// assignment matches the reference bitwise.
__global__ __launch_bounds__(64, 1) void matcher_kernel(
    const float* __restrict__ gious,   // [B, Q, G]
    const int*   __restrict__ nactual, // [B]
    float*       __restrict__ out,     // [2*B*Q]
    int B)
{
  const int b = blockIdx.x;
  const int t = threadIdx.x;

  int nb = nactual[b];
  nb = nb < 0 ? 0 : (nb > GN ? GN : nb);

  // ---- stage cost into registers: c_k[g] = cost[g][4t+k] = -2*gious[b][4t+k][g]
  fv64 c0, c1, c2, c3;
  {
    const float* gb = gious + (size_t)b * QN * GN;
#define LOADK(K, CK)                                                            \
    {                                                                           \
      const float4* rp = (const float4*)(gb + (size_t)(4 * t + K) * GN);        \
      _Pragma("unroll")                                                         \
      for (int g4 = 0; g4 < 16; ++g4) {                                         \
        float4 x = rp[g4];                                                      \
        CK[4 * g4 + 0] = -2.0f * x.x;                                           \
        CK[4 * g4 + 1] = -2.0f * x.y;                                           \
        CK[4 * g4 + 2] = -2.0f * x.z;                                           \
        CK[4 * g4 + 3] = -2.0f * x.w;                                           \
      }                                                                         \
    }
    LOADK(0, c0)
    LOADK(1, c1)
    LOADK(2, c2)
    LOADK(3, c3)
#undef LOADK
  }

  // ---- persistent per-lane state ----
  double v0 = 0, v1 = 0, v2 = 0, v3 = 0;          // v[4t..4t+3]
  int r4c0 = -1, r4c1 = -1, r4c2 = -1, r4c3 = -1; // row4col[4t..4t+3]
  double u = 0.0;                                  // u[t]
  int col4row = -1;                                // col4row[t]

  for (int cur = 0; cur < nb; ++cur) {
    double s0 = DBL_MAX, s1 = DBL_MAX, s2 = DBL_MAX, s3 = DBL_MAX;     // shortest
    double sp0 = DBL_MAX, sp1 = DBL_MAX, sp2 = DBL_MAX, sp3 = DBL_MAX; // SC-masked copy
    int p0 = -1, p1 = -1, p2 = -1, p3 = -1;                            // path
    int scm = 0;  // SC bits for my 4 columns
    int sr  = 0;  // SR flag for my row
    double min_val = 0.0;
    int i = cur;     // wave-uniform (loop counter or readlane-derived)
    int sink = -1;

    while (sink < 0) {
      const int iu = i;
      // cost row iu, my 4 columns — uniform switch, static extracts only
      float cx, cy, cz, cw;
      switch (iu) {
#define CASEK(K) case (K): cx = c0[(K)]; cy = c1[(K)]; cz = c2[(K)]; cw = c3[(K)]; break;
#define C8(Bse) CASEK((Bse)+0) CASEK((Bse)+1) CASEK((Bse)+2) CASEK((Bse)+3) \
                CASEK((Bse)+4) CASEK((Bse)+5) CASEK((Bse)+6) CASEK((Bse)+7)
        C8(0) C8(8) C8(16) C8(24) C8(32) C8(40) C8(48) C8(56)
#undef C8
#undef CASEK
        default: __builtin_unreachable();
      }
      if (t == iu) sr = 1;
      // u[i] broadcast
      double u_i = mkdbl(__builtin_amdgcn_readlane(__double2loint(u), iu),
                         __builtin_amdgcn_readlane(__double2hiint(u), iu));
      // relax (numpy op order: ((min_val + c) - u_i) - v)
      double r;
      r = ((min_val + (double)cx) - u_i) - v0; if (!(scm & 1) && r < s0) { s0 = r; sp0 = r; p0 = iu; }
      r = ((min_val + (double)cy) - u_i) - v1; if (!(scm & 2) && r < s1) { s1 = r; sp1 = r; p1 = iu; }
      r = ((min_val + (double)cz) - u_i) - v2; if (!(scm & 4) && r < s2) { s2 = r; sp2 = r; p2 = iu; }
      r = ((min_val + (double)cw) - u_i) - v3; if (!(scm & 8) && r < s3) { s3 = r; sp3 = r; p3 = iu; }

      // ---- local min VALUE over my non-SC slots (f64 tree, chain-critical) ----
      double mloc = fmin(fmin(sp0, sp1), fmin(sp2, sp3));

      // ---- local argmin slot + packed (bj, row4col) word (off critical path;
      //      overlaps the DPP reduction). Strict < keeps earliest slot = np order.
      double bv = sp0; int bs = 0;
      if (sp1 < bv) { bv = sp1; bs = 1; }
      if (sp2 < bv) { bv = sp2; bs = 2; }
      if (sp3 < bv) { bv = sp3; bs = 3; }
      int rsel = (bs == 0) ? r4c0 : (bs == 1) ? r4c1 : (bs == 2) ? r4c2 : r4c3;
      int packed = ((4 * t + bs) << 8) | (rsel + 1);   // bj in high bits, r4+1 low

      // ---- sortable hi-key (canonicalize -0 -> +0 first) ----
      double mc = mloc + 0.0;
      int mhi = __double2hiint(mc);
      unsigned keyhi = (unsigned)(mhi ^ ((mhi >> 31) | 0x80000000));

      // ---- 6-step u32 DPP min -> lane 63, broadcast ----
      unsigned kx = keyhi;
#define UMSTEP(CTRL, RMASK)                                                     \
      {                                                                         \
        unsigned nk = (unsigned)__builtin_amdgcn_update_dpp(                    \
            (int)kx, (int)kx, CTRL, RMASK, 0xf, false);                         \
        kx = nk < kx ? nk : kx;                                                 \
      }
      UMSTEP(0x111, 0xf)  // row_shr:1
      UMSTEP(0x112, 0xf)  // row_shr:2
      UMSTEP(0x114, 0xf)  // row_shr:4
      UMSTEP(0x118, 0xf)  // row_shr:8
      UMSTEP(0x142, 0xa)  // row_bcast15
      UMSTEP(0x143, 0xc)  // row_bcast31 -> lane 63 global min
#undef UMSTEP
      unsigned minKH = (unsigned)__builtin_amdgcn_readlane((int)kx, 63);

      unsigned long long ball = __ballot(keyhi == minKH);
      double mv; int packedw;
      if (__popcll(ball) == 1) {
        // unique min-hi lane holds the unique global min value (exact).
        int fl = (int)__builtin_ctzll(ball);
        packedw = __builtin_amdgcn_readlane(packed, fl);
        mv = mkdbl(__builtin_amdgcn_readlane(__double2loint(mloc), fl),
                   __builtin_amdgcn_readlane(__double2hiint(mloc), fl));
      } else {
        // rare near-tie: exact (value, packed-index) pair argmin, np tie-break.
        double av = mloc; int ap = packed;
#define AM_STEP(CTRL, RMASK)                                                    \
        {                                                                       \
          int lo  = __double2loint(av), hi = __double2hiint(av);                \
          int nlo = __builtin_amdgcn_update_dpp(lo, lo, CTRL, RMASK, 0xf, false);\
          int nhi = __builtin_amdgcn_update_dpp(hi, hi, CTRL, RMASK, 0xf, false);\
          int nap = __builtin_amdgcn_update_dpp(ap, ap, CTRL, RMASK, 0xf, false);\
          double nv = mkdbl(nlo, nhi);                                          \
          bool take = (nv < av) || (nv == av && nap < ap);                      \
          av = take ? nv : av;                                                  \
          ap = take ? nap : ap;                                                 \
        }
        AM_STEP(0x111, 0xf)
        AM_STEP(0x112, 0xf)
        AM_STEP(0x114, 0xf)
        AM_STEP(0x118, 0xf)
        AM_STEP(0x142, 0xa)
        AM_STEP(0x143, 0xc)
#undef AM_STEP
        packedw = __builtin_amdgcn_readlane(ap, 63);
        mv = mkdbl(__builtin_amdgcn_readlane(__double2loint(av), 63),
                   __builtin_amdgcn_readlane(__double2hiint(av), 63));
      }

      min_val = mv;
      int jstar = packedw >> 8;
      int r4    = (packedw & 0xFF) - 1;
      int jo = jstar >> 2, sl = jstar & 3;
      // SC[jstar] = 1 (and mask its sp)
      if (t == jo) {
        scm |= (1 << sl);
        if      (sl == 0) sp0 = DBL_MAX;
        else if (sl == 1) sp1 = DBL_MAX;
        else if (sl == 2) sp2 = DBL_MAX;
        else              sp3 = DBL_MAX;
      }
      if (r4 < 0) sink = jstar;
      else        i = r4;
    }

    // ---- dual update (reference order; real shortest, pre-augment col4row)
    {
      int c  = col4row < 0 ? 0 : col4row;
      int ow = (c >> 2) & 63, sl2 = c & 3;
      double g0 = __shfl(s0, ow, 64);
      double g1 = __shfl(s1, ow, 64);
      double g2 = __shfl(s2, ow, 64);
      double g3 = __shfl(s3, ow, 64);
      double s_c = (sl2 == 0) ? g0 : (sl2 == 1) ? g1 : (sl2 == 2) ? g2 : g3;
      if (t == cur)  u += min_val;
      else if (sr)   u += min_val - s_c;
      if (scm & 1) v0 -= min_val - s0;
      if (scm & 2) v1 -= min_val - s1;
      if (scm & 4) v2 -= min_val - s2;
      if (scm & 8) v3 -= min_val - s3;
    }

    // ---- augment along alternating path (uniform walk, lockstep)
    {
      int j = sink;
      while (true) {
        int jo = j >> 2, sl = j & 3;
        int pv = (sl == 0) ? p0 : (sl == 1) ? p1 : (sl == 2) ? p2 : p3;
        int pi = __builtin_amdgcn_readlane(pv, jo);
        if (t == jo) {
          if      (sl == 0) r4c0 = pi;
          else if (sl == 1) r4c1 = pi;
          else if (sl == 2) r4c2 = pi;
          else              r4c3 = pi;
        }
        int jn = __builtin_amdgcn_readlane(col4row, pi);
        if (t == pi) col4row = j;
        j = jn;
        if (pi == cur) break;
      }
    }
  }

  // ---- outputs (every element written -> poison-safe) ----
  {
    const size_t BQ = (size_t)B * QN;
    int base = b * QN + 4 * t;
    float4 inds = make_float4(r4c0 >= 0 ? (float)r4c0 : 0.0f,
                              r4c1 >= 0 ? (float)r4c1 : 0.0f,
                              r4c2 >= 0 ? (float)r4c2 : 0.0f,
                              r4c3 >= 0 ? (float)r4c3 : 0.0f);
    float4 mask = make_float4(r4c0 >= 0 ? 1.0f : 0.0f,
                              r4c1 >= 0 ? 1.0f : 0.0f,
                              r4c2 >= 0 ? 1.0f : 0.0f,
                              r4c3 >= 0 ? 1.0f : 0.0f);
    *(float4*)&out[base]      = inds;
    *(float4*)&out[BQ + base] = mask;
  }
}

extern "C" void kernel_launch(void* const* d_in, const int* in_sizes, int n_in,
                              void* d_out, int out_size, void* d_ws, size_t ws_size,
                              hipStream_t stream) {
  // inputs: 0 last_sem_cls_scores (unused), 1 gious [B,Q,G], 2 positive_map (unused),
  //         3 sem_cls_label (unused), 4 nactual_gt [B]
  const float* gious   = (const float*)d_in[1];
  const int*   nactual = (const int*)d_in[4];
  float*       out     = (float*)d_out;
  const int B = in_sizes[4];

  matcher_kernel<<<B, 64, 0, stream>>>(gious, nactual, out, B);
}